// Round 5
// baseline (5837.002 us; speedup 1.0000x reference)
//
#include <hip/hip_runtime.h>

constexpr int BN = 512;
constexpr int NITER = 50;

#define CEXP  (-28.853900817779268f)  /* -log2(e)/0.05 */
#define ESH   (14.0f)                 /* E' = 2^(M*CEXP + 14) in fp16 */
#define L2TAU (9.965784284662087f)    /* log2(1000) */

typedef unsigned int u32;

__device__ __forceinline__ float fexp2(float x) { return __builtin_amdgcn_exp2f(x); }
__device__ __forceinline__ float flog2(float x) { return __builtin_amdgcn_logf(x); }

__device__ __forceinline__ float nr_rcp(float x) {
    float r = __builtin_amdgcn_rcpf(x);
    return fmaf(r, fmaf(-x, r, 1.0f), r);
}

template <int CTRL>
__device__ __forceinline__ float dppx(float x) {
    return __int_as_float(__builtin_amdgcn_update_dpp(
        0, __float_as_int(x), CTRL, 0xF, 0xF, true));
}

__device__ __forceinline__ float bfly_sum(float x) {
    x += dppx<0xB1>(x);
    x += dppx<0x4E>(x);
    x += dppx<0x141>(x);
    x += dppx<0x140>(x);
    x += __shfl_xor(x, 16, 64);
    x += __shfl_xor(x, 32, 64);
    return x;
}
__device__ __forceinline__ float bfly_max(float x) {
    x = fmaxf(x, dppx<0xB1>(x));
    x = fmaxf(x, dppx<0x4E>(x));
    x = fmaxf(x, dppx<0x141>(x));
    x = fmaxf(x, dppx<0x140>(x));
    x = fmaxf(x, __shfl_xor(x, 16, 64));
    x = fmaxf(x, __shfl_xor(x, 32, 64));
    return x;
}

// accLo += f16lo(e2)*pLo ; accHi += f16hi(e2)*pHi  (one VALU op each)
__device__ __forceinline__ void fma_mix2(float& accLo, float& accHi, u32 e2,
                                         float pLo, float pHi) {
    asm("v_fma_mix_f32 %0, %2, %3, %0 op_sel_hi:[1,0,0]\n\t"
        "v_fma_mix_f32 %1, %2, %4, %1 op_sel:[1,0,0] op_sel_hi:[1,0,0]"
        : "+v"(accLo), "+v"(accHi)
        : "v"(e2), "v"(pLo), "v"(pHi));
}

// ---------------- Kernel A: E' = fp16(2^(M*CEXP+14)), stored transposed ----------------
__global__ __launch_bounds__(256)
void prep_exp_t(const float* __restrict__ X, float* __restrict__ out)
{
    const int blk  = blockIdx.x;
    const int b    = blk >> 4;
    const int tile = blk & 15;
    const int i0   = (tile >> 2) << 7;
    const int j0   = (tile & 3) << 7;
    const int tid  = threadIdx.x;

    const float* __restrict__ Mb = X + (size_t)b * (BN * BN);
    _Float16* __restrict__ Et = reinterpret_cast<_Float16*>(out + (size_t)b * (BN * BN));

    __shared__ _Float16 T[128][130];

    #pragma unroll
    for (int k = 0; k < 16; ++k) {
        int idx = tid + (k << 8);
        int fi  = idx >> 5;
        int fj  = idx & 31;
        float4 m = *reinterpret_cast<const float4*>(Mb + (size_t)(i0 + fi) * BN + j0 + (fj << 2));
        T[(fj << 2) + 0][fi] = (_Float16)fexp2(fmaf(m.x, CEXP, ESH));
        T[(fj << 2) + 1][fi] = (_Float16)fexp2(fmaf(m.y, CEXP, ESH));
        T[(fj << 2) + 2][fi] = (_Float16)fexp2(fmaf(m.z, CEXP, ESH));
        T[(fj << 2) + 3][fi] = (_Float16)fexp2(fmaf(m.w, CEXP, ESH));
    }
    __syncthreads();
    #pragma unroll
    for (int k = 0; k < 32; ++k) {
        int o  = tid + (k << 8);
        int j  = o >> 6;
        int c2 = o & 63;
        u32 val = *reinterpret_cast<const u32*>(&T[j][c2 << 1]);
        *reinterpret_cast<u32*>(Et + (size_t)(j0 + j) * BN + i0 + (c2 << 1)) = val;
    }
}

// ---------------- Kernel B: pair-split iterations (2 blocks per matrix) ----------------
// Exchange data + flags live in d_ws. Flags are memset to 0 on stream before
// every launch, so the release/acquire protocol starts clean on each replay.
__global__ __launch_bounds__(1024, 4)
void sinkhorn_pair(const float* __restrict__ X, float* __restrict__ out,
                   float* __restrict__ xdata, int* __restrict__ flags, int batch)
{
    const int g    = blockIdx.x;
    const int b    = (g >= batch) ? (g - batch) : g;
    const int sub  = (g >= batch) ? 1 : 0;
    const int t    = threadIdx.x;
    const int lane = t & 63;
    const int w    = t >> 6;            // 0..15

    float* __restrict__ slot = out + (size_t)b * (BN * BN);
    const u32* __restrict__ Et4 = reinterpret_cast<const u32*>(slot);

    float* __restrict__ xbase = xdata + (size_t)b * 4096;
    int* __restrict__ F   = flags + b * 128;
    int* __restrict__ Fme = F + sub * 64;
    int* __restrict__ Fpt = F + (1 - sub) * 64;

    __shared__ float ah[BN], bh[BN], lu[BN], lv[BN], pv[BN];
    __shared__ float tpart[16][BN];
    __shared__ float wmaxlu[8], wmaxlv[16];
    __shared__ float s_pvmax;

    if (t < BN) {
        ah[t] = 0.f; bh[t] = 0.f;
        lu[t] = -9.f; lv[t] = -9.f;
        pv[t] = 0x1p-9f;
    }
    __syncthreads();

    for (int it = 0; it < NITER; ++it) {
        float pr[8];
        *reinterpret_cast<float4*>(&pr[0]) = *reinterpret_cast<const float4*>(&pv[lane * 8]);
        *reinterpret_cast<float4*>(&pr[4]) = *reinterpret_cast<const float4*>(&pv[lane * 8 + 4]);

        float acc[8] = {0, 0, 0, 0, 0, 0, 0, 0};
        float vml = -1e30f;
        const int jb0 = (sub << 8) + (w << 4);   // 16 columns per wave

        uint4 e[8], f[8];
        #pragma unroll
        for (int c = 0; c < 8; ++c)
            e[c] = *reinterpret_cast<const uint4*>(Et4 + (size_t)(jb0 + c) * 256 + lane * 4);
        #pragma unroll
        for (int c = 0; c < 8; ++c)
            f[c] = *reinterpret_cast<const uint4*>(Et4 + (size_t)(jb0 + 8 + c) * 256 + lane * 4);

        auto dogroup = [&](const uint4* eg, int jb) {
            const float4 bh4 = *reinterpret_cast<const float4*>(&bh[jb]);
            float q[4], lvv[4];
            #pragma unroll
            for (int c = 0; c < 4; ++c) {
                float s0 = 0.f, s1 = 0.f;
                fma_mix2(s0, s1, eg[c].x, pr[0], pr[1]);
                fma_mix2(s0, s1, eg[c].y, pr[2], pr[3]);
                fma_mix2(s0, s1, eg[c].z, pr[4], pr[5]);
                fma_mix2(s0, s1, eg[c].w, pr[6], pr[7]);
                float s = bfly_sum(s0 + s1) * 0x1p-14f;
                q[c] = nr_rcp(s);
                const float bj = (c == 0) ? bh4.x : (c == 1) ? bh4.y : (c == 2) ? bh4.z : bh4.w;
                lvv[c] = -bj - flog2(s);
                vml = fmaxf(vml, lvv[c]);
            }
            if (lane == 0)
                *reinterpret_cast<float4*>(&lv[jb]) = make_float4(lvv[0], lvv[1], lvv[2], lvv[3]);
            #pragma unroll
            for (int c = 0; c < 4; ++c) {
                fma_mix2(acc[0], acc[1], eg[c].x, q[c], q[c]);
                fma_mix2(acc[2], acc[3], eg[c].y, q[c], q[c]);
                fma_mix2(acc[4], acc[5], eg[c].z, q[c], q[c]);
                fma_mix2(acc[6], acc[7], eg[c].w, q[c], q[c]);
            }
        };
        dogroup(e + 0, jb0);
        dogroup(e + 4, jb0 + 4);
        dogroup(f + 0, jb0 + 8);
        dogroup(f + 4, jb0 + 12);

        *reinterpret_cast<float4*>(&tpart[w][lane * 8]) =
            make_float4(acc[0], acc[1], acc[2], acc[3]);
        *reinterpret_cast<float4*>(&tpart[w][lane * 8 + 4]) =
            make_float4(acc[4], acc[5], acc[6], acc[7]);
        if (lane == 0) wmaxlv[w] = vml;
        __syncthreads();

        // ---- own partial t + exchange through d_ws ----
        float* xd_me = xbase + (it & 1) * 2048 + sub * 1024;
        const float* xd_pt = xbase + (it & 1) * 2048 + (1 - sub) * 1024;

        float tto = 0.f;
        if (t < BN) {
            float p0 = 0, p1 = 0, p2 = 0, p3 = 0;
            #pragma unroll
            for (int w2 = 0; w2 < 16; w2 += 4) {
                p0 += tpart[w2 + 0][t];
                p1 += tpart[w2 + 1][t];
                p2 += tpart[w2 + 2][t];
                p3 += tpart[w2 + 3][t];
            }
            tto = (p0 + p1) + (p2 + p3);       // raw (x 2^14) partial
            xd_me[t] = tto;
        }
        if (t == 0) {
            float m = wmaxlv[0];
            #pragma unroll
            for (int i2 = 1; i2 < 16; ++i2) m = fmaxf(m, wmaxlv[i2]);
            xd_me[BN] = m;
        }
        __threadfence();
        __syncthreads();
        if (t == 0) {
            __hip_atomic_store(&Fme[it], it + 1, __ATOMIC_RELEASE, __HIP_MEMORY_SCOPE_AGENT);
            while (__hip_atomic_load(&Fpt[it], __ATOMIC_ACQUIRE, __HIP_MEMORY_SCOPE_AGENT) < it + 1) {}
        }
        __syncthreads();

        float lun = 0.f, tt = 0.f;
        if (t < BN) {
            tt  = (tto + xd_pt[t]) * 0x1p-14f;   // commutative add -> identical in both blocks
            lun = -ah[t] - flog2(tt);
            float m = bfly_max(lun);
            if (lane == 0) wmaxlu[w] = m;
        }
        if (t == 0) s_pvmax = xd_pt[BN];
        __syncthreads();

        if (t < BN) {
            float mlu = wmaxlu[0];
            #pragma unroll
            for (int i2 = 1; i2 < 8; ++i2) mlu = fmaxf(mlu, wmaxlu[i2]);
            float mlv = s_pvmax;
            #pragma unroll
            for (int i2 = 0; i2 < 16; ++i2) mlv = fmaxf(mlv, wmaxlv[i2]);
            if (mlu > L2TAU || mlv > L2TAU) {
                float an = ah[t] + lun;
                ah[t] = an;
                lu[t] = -9.f;
                pv[t] = fexp2(an - 9.0f);
                bh[t] += lv[t];
                lv[t] = -9.f;
            } else {
                lu[t] = lun;
                pv[t] = nr_rcp(tt);
            }
        }
        __syncthreads();
    }

    if (t < BN) {
        pv[t] = ah[t] + lu[t];           // cu (all rows)
        lv[t] = bh[t] + lv[t];           // cv (valid for own columns)
    }
    __syncthreads();

    // Gamma for own 256 columns, recomputed from fp32 M (d_ws untouched)
    const int j  = (sub << 8) + (t & 255);
    const int i0 = (t >> 8) << 7;
    const float cvj = lv[j];
    const float* __restrict__ Mb = X + (size_t)b * (BN * BN);
    #pragma unroll 4
    for (int i = i0; i < i0 + 128; ++i)
        slot[(size_t)i * BN + j] = fexp2(fmaf(Mb[(size_t)i * BN + j], CEXP, pv[i] + cvj));
}

// ---------------- Fallback: single-block-per-matrix (proven 807us) ----------------
__global__ __launch_bounds__(1024, 4)
void sinkhorn_iter(const float* __restrict__ X, float* __restrict__ out)
{
    const int b    = blockIdx.x;
    const int t    = threadIdx.x;
    const int lane = t & 63;
    const int w    = t >> 6;            // 0..15

    const u32* __restrict__ Et4 =
        reinterpret_cast<const u32*>(out + (size_t)b * (BN * BN));

    __shared__ float ah[BN], bh[BN], lu[BN], lv[BN], pv[BN];
    __shared__ float tpart[16][BN];
    __shared__ float wmaxlu[8], wmaxlv[16];

    if (t < BN) {
        ah[t] = 0.f; bh[t] = 0.f;
        lu[t] = -9.f; lv[t] = -9.f;
        pv[t] = 0x1p-9f;
    }
    __syncthreads();

    for (int it = 0; it < NITER; ++it) {
        float pr[8];
        *reinterpret_cast<float4*>(&pr[0]) = *reinterpret_cast<const float4*>(&pv[lane * 8]);
        *reinterpret_cast<float4*>(&pr[4]) = *reinterpret_cast<const float4*>(&pv[lane * 8 + 4]);

        float acc[8] = {0, 0, 0, 0, 0, 0, 0, 0};
        float vml = -1e30f;
        const int jb0 = w << 5;

        uint4 e[4], f[4];
        #pragma unroll
        for (int c = 0; c < 4; ++c)
            e[c] = *reinterpret_cast<const uint4*>(Et4 + (size_t)(jb0 + c) * 256 + lane * 4);

        #pragma unroll
        for (int k = 0; k < 8; ++k) {
            const int jb = jb0 + 4 * k;
            if (k < 7) {
                #pragma unroll
                for (int c = 0; c < 4; ++c)
                    f[c] = *reinterpret_cast<const uint4*>(Et4 + (size_t)(jb + 4 + c) * 256 + lane * 4);
            }
            const float4 bh4 = *reinterpret_cast<const float4*>(&bh[jb]);
            float q[4], lvv[4];
            #pragma unroll
            for (int c = 0; c < 4; ++c) {
                float s0 = 0.f, s1 = 0.f;
                fma_mix2(s0, s1, e[c].x, pr[0], pr[1]);
                fma_mix2(s0, s1, e[c].y, pr[2], pr[3]);
                fma_mix2(s0, s1, e[c].z, pr[4], pr[5]);
                fma_mix2(s0, s1, e[c].w, pr[6], pr[7]);
                float s = bfly_sum(s0 + s1) * 0x1p-14f;
                q[c] = nr_rcp(s);
                const float bj = (c == 0) ? bh4.x : (c == 1) ? bh4.y : (c == 2) ? bh4.z : bh4.w;
                lvv[c] = -bj - flog2(s);
                vml = fmaxf(vml, lvv[c]);
            }
            if (lane == 0)
                *reinterpret_cast<float4*>(&lv[jb]) = make_float4(lvv[0], lvv[1], lvv[2], lvv[3]);
            #pragma unroll
            for (int c = 0; c < 4; ++c) {
                fma_mix2(acc[0], acc[1], e[c].x, q[c], q[c]);
                fma_mix2(acc[2], acc[3], e[c].y, q[c], q[c]);
                fma_mix2(acc[4], acc[5], e[c].z, q[c], q[c]);
                fma_mix2(acc[6], acc[7], e[c].w, q[c], q[c]);
            }
            #pragma unroll
            for (int c = 0; c < 4; ++c) e[c] = f[c];
        }

        *reinterpret_cast<float4*>(&tpart[w][lane * 8]) =
            make_float4(acc[0], acc[1], acc[2], acc[3]);
        *reinterpret_cast<float4*>(&tpart[w][lane * 8 + 4]) =
            make_float4(acc[4], acc[5], acc[6], acc[7]);
        if (lane == 0) wmaxlv[w] = vml;
        __syncthreads();

        float lun = 0.f, tt = 0.f;
        if (t < BN) {
            float p0 = 0, p1 = 0, p2 = 0, p3 = 0;
            #pragma unroll
            for (int w2 = 0; w2 < 16; w2 += 4) {
                p0 += tpart[w2 + 0][t];
                p1 += tpart[w2 + 1][t];
                p2 += tpart[w2 + 2][t];
                p3 += tpart[w2 + 3][t];
            }
            tt  = ((p0 + p1) + (p2 + p3)) * 0x1p-14f;
            lun = -ah[t] - flog2(tt);
            float m = bfly_max(lun);
            if (lane == 0) wmaxlu[w] = m;
        }
        __syncthreads();

        if (t < BN) {
            float mlu = wmaxlu[0], mlv = wmaxlv[0];
            #pragma unroll
            for (int i2 = 1; i2 < 8; ++i2)  mlu = fmaxf(mlu, wmaxlu[i2]);
            #pragma unroll
            for (int i2 = 1; i2 < 16; ++i2) mlv = fmaxf(mlv, wmaxlv[i2]);
            if (mlu > L2TAU || mlv > L2TAU) {
                float an = ah[t] + lun;
                ah[t] = an;
                lu[t] = -9.f;
                pv[t] = fexp2(an - 9.0f);
                bh[t] += lv[t];
                lv[t] = -9.f;
            } else {
                lu[t] = lun;
                pv[t] = nr_rcp(tt);
            }
        }
        __syncthreads();
    }

    if (t < BN) {
        pv[t] = ah[t] + lu[t];
        lv[t] = bh[t] + lv[t];
    }
    __syncthreads();

    const int j  = t & 511;
    const int i0 = (t >> 9) * 256;
    const float cvj = lv[j];
    const float* __restrict__ Mb = X + (size_t)b * (BN * BN);
    float* __restrict__ Gb = out + (size_t)b * (BN * BN);
    #pragma unroll 4
    for (int i = i0; i < i0 + 256; ++i)
        Gb[(size_t)i * BN + j] = fexp2(fmaf(Mb[(size_t)i * BN + j], CEXP, pv[i] + cvj));
}

extern "C" void kernel_launch(void* const* d_in, const int* in_sizes, int n_in,
                              void* d_out, int out_size, void* d_ws, size_t ws_size,
                              hipStream_t stream)
{
    const float* X = (const float*)d_in[0];
    float* out = (float*)d_out;
    const int batch = in_sizes[0] / (BN * BN);   // 128

    prep_exp_t<<<batch * 16, 256, 0, stream>>>(X, out);

    const size_t flag_bytes = (size_t)batch * 128 * sizeof(int);       // 64 KB
    const size_t data_bytes = (size_t)batch * 4096 * sizeof(float);    // 2 MB
    if (ws_size >= flag_bytes + data_bytes) {
        int*   flags = (int*)d_ws;
        float* xdata = (float*)((char*)d_ws + flag_bytes);
        hipMemsetAsync(d_ws, 0, flag_bytes, stream);
        sinkhorn_pair<<<batch * 2, 1024, 0, stream>>>(X, out, xdata, flags, batch);
    } else {
        sinkhorn_iter<<<batch, 1024, 0, stream>>>(X, out);
    }
}

// Round 6
// 972.836 us; speedup vs baseline: 6.0000x; 6.0000x over previous
//
#include <hip/hip_runtime.h>

constexpr int BN = 512;
constexpr int NITER = 50;

#define CEXP  (-28.853900817779268f)  /* -log2(e)/0.05 */
#define ESH   (14.0f)                 /* E' = 2^(M*CEXP + 14) in fp16 */
#define L2TAU (9.965784284662087f)    /* log2(1000) */

typedef unsigned int u32;

__device__ __forceinline__ float fexp2(float x) { return __builtin_amdgcn_exp2f(x); }
__device__ __forceinline__ float flog2(float x) { return __builtin_amdgcn_logf(x); }

__device__ __forceinline__ float nr_rcp(float x) {
    float r = __builtin_amdgcn_rcpf(x);
    return fmaf(r, fmaf(-x, r, 1.0f), r);
}

template <int CTRL>
__device__ __forceinline__ float dppx(float x) {
    return __int_as_float(__builtin_amdgcn_update_dpp(
        0, __float_as_int(x), CTRL, 0xF, 0xF, true));
}

__device__ __forceinline__ float bfly_sum(float x) {
    x += dppx<0xB1>(x);            // xor1 (quad_perm)
    x += dppx<0x4E>(x);            // xor2 (quad_perm)
    x += dppx<0x141>(x);           // xor4 (half_mirror)
    x += dppx<0x140>(x);           // xor8 (mirror)
    x += __shfl_xor(x, 16, 64);
    x += __shfl_xor(x, 32, 64);
    return x;
}
__device__ __forceinline__ float bfly_max(float x) {
    x = fmaxf(x, dppx<0xB1>(x));
    x = fmaxf(x, dppx<0x4E>(x));
    x = fmaxf(x, dppx<0x141>(x));
    x = fmaxf(x, dppx<0x140>(x));
    x = fmaxf(x, __shfl_xor(x, 16, 64));
    x = fmaxf(x, __shfl_xor(x, 32, 64));
    return x;
}

// accLo += f16lo(e2)*pLo ; accHi += f16hi(e2)*pHi  (one VALU op each)
__device__ __forceinline__ void fma_mix2(float& accLo, float& accHi, u32 e2,
                                         float pLo, float pHi) {
    asm("v_fma_mix_f32 %0, %2, %3, %0 op_sel_hi:[1,0,0]\n\t"
        "v_fma_mix_f32 %1, %2, %4, %1 op_sel:[1,0,0] op_sel_hi:[1,0,0]"
        : "+v"(accLo), "+v"(accHi)
        : "v"(e2), "v"(pLo), "v"(pHi));
}

// ---------------- Kernel A: E' = fp16(2^(M*CEXP+14)), stored transposed ----------------
__global__ __launch_bounds__(256)
void prep_exp_t(const float* __restrict__ X, float* __restrict__ out)
{
    const int blk  = blockIdx.x;
    const int b    = blk >> 4;
    const int tile = blk & 15;
    const int i0   = (tile >> 2) << 7;
    const int j0   = (tile & 3) << 7;
    const int tid  = threadIdx.x;

    const float* __restrict__ Mb = X + (size_t)b * (BN * BN);
    _Float16* __restrict__ Et = reinterpret_cast<_Float16*>(out + (size_t)b * (BN * BN));

    __shared__ _Float16 T[128][130];

    #pragma unroll
    for (int k = 0; k < 16; ++k) {
        int idx = tid + (k << 8);
        int fi  = idx >> 5;
        int fj  = idx & 31;
        float4 m = *reinterpret_cast<const float4*>(Mb + (size_t)(i0 + fi) * BN + j0 + (fj << 2));
        T[(fj << 2) + 0][fi] = (_Float16)fexp2(fmaf(m.x, CEXP, ESH));
        T[(fj << 2) + 1][fi] = (_Float16)fexp2(fmaf(m.y, CEXP, ESH));
        T[(fj << 2) + 2][fi] = (_Float16)fexp2(fmaf(m.z, CEXP, ESH));
        T[(fj << 2) + 3][fi] = (_Float16)fexp2(fmaf(m.w, CEXP, ESH));
    }
    __syncthreads();
    #pragma unroll
    for (int k = 0; k < 32; ++k) {
        int o  = tid + (k << 8);
        int j  = o >> 6;
        int c2 = o & 63;
        u32 val = *reinterpret_cast<const u32*>(&T[j][c2 << 1]);
        *reinterpret_cast<u32*>(Et + (size_t)(j0 + j) * BN + i0 + (c2 << 1)) = val;
    }
}

// ---------------- Kernel B: 50 iterations, deep prefetch (1 block/matrix) ----------------
__global__ __launch_bounds__(1024)
void sinkhorn_iter2(const float* __restrict__ X, float* __restrict__ out,
                    float* __restrict__ cucv)
{
    const int b    = blockIdx.x;
    const int t    = threadIdx.x;
    const int lane = t & 63;
    const int w    = t >> 6;            // 0..15

    const u32* __restrict__ Et4 =
        reinterpret_cast<const u32*>(out + (size_t)b * (BN * BN));

    __shared__ float ah[BN], bh[BN], lu[BN], lv[BN], pv[BN];
    __shared__ float tpart[16][BN];
    __shared__ float wmaxlu[8], wmaxlv[16];

    if (t < BN) {
        ah[t] = 0.f; bh[t] = 0.f;
        lu[t] = -9.f; lv[t] = -9.f;
        pv[t] = 0x1p-9f;
    }
    __syncthreads();

    const int jb0 = w << 5;              // 32 columns per wave
    uint4 e[8], f[8];
    #pragma unroll
    for (int c = 0; c < 8; ++c)          // preload group 0
        e[c] = *reinterpret_cast<const uint4*>(Et4 + (size_t)(jb0 + c) * 256 + (lane << 2));

    for (int it = 0; it < NITER; ++it) {
        float pr[8];
        *reinterpret_cast<float4*>(&pr[0]) = *reinterpret_cast<const float4*>(&pv[lane * 8]);
        *reinterpret_cast<float4*>(&pr[4]) = *reinterpret_cast<const float4*>(&pv[lane * 8 + 4]);

        float acc[8] = {0, 0, 0, 0, 0, 0, 0, 0};
        float vml = -1e30f;

        #pragma unroll
        for (int g = 0; g < 4; ++g) {
            const int jb = jb0 + (g << 3);
            const int jn = jb0 + (((g + 1) & 3) << 3);   // g==3 prefetches next iter's group 0

            #pragma unroll
            for (int c = 0; c < 8; ++c)
                f[c] = *reinterpret_cast<const uint4*>(Et4 + (size_t)(jn + c) * 256 + (lane << 2));

            float sc[8];
            #pragma unroll
            for (int c = 0; c < 8; ++c) {
                float s0 = 0.f, s1 = 0.f;
                fma_mix2(s0, s1, e[c].x, pr[0], pr[1]);
                fma_mix2(s0, s1, e[c].y, pr[2], pr[3]);
                fma_mix2(s0, s1, e[c].z, pr[4], pr[5]);
                fma_mix2(s0, s1, e[c].w, pr[6], pr[7]);
                sc[c] = s0 + s1;
            }
            #pragma unroll
            for (int c = 0; c < 8; ++c) sc[c] = bfly_sum(sc[c]);   // 8 independent chains

            float q[8];
            #pragma unroll
            for (int c = 0; c < 8; ++c) {
                float s = sc[c] * 0x1p-14f;
                q[c] = nr_rcp(s);
                float lvj = -bh[jb + c] - flog2(s);
                vml = fmaxf(vml, lvj);
                if (lane == 0) lv[jb + c] = lvj;
            }
            #pragma unroll
            for (int c = 0; c < 8; ++c) {
                fma_mix2(acc[0], acc[1], e[c].x, q[c], q[c]);
                fma_mix2(acc[2], acc[3], e[c].y, q[c], q[c]);
                fma_mix2(acc[4], acc[5], e[c].z, q[c], q[c]);
                fma_mix2(acc[6], acc[7], e[c].w, q[c], q[c]);
            }
            #pragma unroll
            for (int c = 0; c < 8; ++c) e[c] = f[c];
        }

        *reinterpret_cast<float4*>(&tpart[w][lane * 8]) =
            make_float4(acc[0], acc[1], acc[2], acc[3]);
        *reinterpret_cast<float4*>(&tpart[w][lane * 8 + 4]) =
            make_float4(acc[4], acc[5], acc[6], acc[7]);
        if (lane == 0) wmaxlv[w] = vml;
        __syncthreads();

        float lun = 0.f, tt = 0.f;
        if (t < BN) {
            float p0 = 0, p1 = 0, p2 = 0, p3 = 0;
            #pragma unroll
            for (int w2 = 0; w2 < 16; w2 += 4) {
                p0 += tpart[w2 + 0][t];
                p1 += tpart[w2 + 1][t];
                p2 += tpart[w2 + 2][t];
                p3 += tpart[w2 + 3][t];
            }
            tt  = ((p0 + p1) + (p2 + p3)) * 0x1p-14f;
            lun = -ah[t] - flog2(tt);
            float m = bfly_max(lun);
            if (lane == 0) wmaxlu[w] = m;
        }
        __syncthreads();

        if (t < BN) {
            float mlu = wmaxlu[0], mlv = wmaxlv[0];
            #pragma unroll
            for (int i2 = 1; i2 < 8; ++i2)  mlu = fmaxf(mlu, wmaxlu[i2]);
            #pragma unroll
            for (int i2 = 1; i2 < 16; ++i2) mlv = fmaxf(mlv, wmaxlv[i2]);
            if (mlu > L2TAU || mlv > L2TAU) {
                float an = ah[t] + lun;
                ah[t] = an;
                lu[t] = -9.f;
                pv[t] = fexp2(an - 9.0f);
                bh[t] += lv[t];
                lv[t] = -9.f;
            } else {
                lu[t] = lun;
                pv[t] = nr_rcp(tt);
            }
        }
        __syncthreads();
    }

    if (cucv != nullptr) {
        // hand off potentials; Gamma produced by gamma_out on the full chip
        if (t < BN) {
            cucv[(size_t)b * 1024 + t]       = ah[t] + lu[t];
            cucv[(size_t)b * 1024 + 512 + t] = bh[t] + lv[t];
        }
    } else {
        // fused fallback epilogue (ws too small) — block-uniform branch
        if (t < BN) {
            pv[t] = ah[t] + lu[t];
            lv[t] = bh[t] + lv[t];
        }
        __syncthreads();
        const int j  = t & 511;
        const int i0 = (t >> 9) * 256;
        const float cvj = lv[j];
        const float* __restrict__ Mb = X + (size_t)b * (BN * BN);
        float* __restrict__ Gb = out + (size_t)b * (BN * BN);
        #pragma unroll 4
        for (int i = i0; i < i0 + 256; ++i)
            Gb[(size_t)i * BN + j] = fexp2(fmaf(Mb[(size_t)i * BN + j], CEXP, pv[i] + cvj));
    }
}

// ---------------- Kernel C: Gamma epilogue on the full chip ----------------
__global__ __launch_bounds__(256)
void gamma_out(const float* __restrict__ X, float* __restrict__ out,
               const float* __restrict__ cucv)
{
    const int blk  = blockIdx.x;
    const int b    = blk >> 4;
    const int tile = blk & 15;       // 32 rows per tile
    const int tid  = threadIdx.x;
    const int i0   = tile << 5;

    __shared__ float cu[32];
    __shared__ float cv[BN];

    if (tid < 32) cu[tid] = cucv[(size_t)b * 1024 + i0 + tid];
    cv[tid]        = cucv[(size_t)b * 1024 + 512 + tid];
    cv[tid + 256]  = cucv[(size_t)b * 1024 + 768 + tid];
    __syncthreads();

    const float* __restrict__ Mb = X + (size_t)b * (BN * BN);
    float* __restrict__ Gb = out + (size_t)b * (BN * BN);
    const float4* __restrict__ cv4 = reinterpret_cast<const float4*>(cv);

    #pragma unroll
    for (int k = 0; k < 16; ++k) {
        int idx = tid + (k << 8);        // 0..4095 float4s in this 32x512 tile
        int r   = idx >> 7;              // 0..31
        int c4  = idx & 127;             // float4 column index
        int i   = i0 + r;
        float4 m = *reinterpret_cast<const float4*>(Mb + (size_t)i * BN + (c4 << 2));
        float4 c = cv4[c4];
        float cui = cu[r];
        float4 g;
        g.x = fexp2(fmaf(m.x, CEXP, cui + c.x));
        g.y = fexp2(fmaf(m.y, CEXP, cui + c.y));
        g.z = fexp2(fmaf(m.z, CEXP, cui + c.z));
        g.w = fexp2(fmaf(m.w, CEXP, cui + c.w));
        *reinterpret_cast<float4*>(Gb + (size_t)i * BN + (c4 << 2)) = g;
    }
}

extern "C" void kernel_launch(void* const* d_in, const int* in_sizes, int n_in,
                              void* d_out, int out_size, void* d_ws, size_t ws_size,
                              hipStream_t stream)
{
    const float* X = (const float*)d_in[0];
    float* out = (float*)d_out;
    const int batch = in_sizes[0] / (BN * BN);   // 128

    prep_exp_t<<<batch * 16, 256, 0, stream>>>(X, out);

    const size_t cucv_bytes = (size_t)batch * 1024 * sizeof(float);  // 512 KB
    if (ws_size >= cucv_bytes) {
        float* cucv = (float*)d_ws;
        sinkhorn_iter2<<<batch, 1024, 0, stream>>>(X, out, cucv);
        gamma_out<<<batch * 16, 256, 0, stream>>>(X, out, cucv);
    } else {
        sinkhorn_iter2<<<batch, 1024, 0, stream>>>(X, out, nullptr);
    }
}

// Round 7
// 709.166 us; speedup vs baseline: 8.2308x; 1.3718x over previous
//
#include <hip/hip_runtime.h>

constexpr int BN = 512;
constexpr int NITER = 50;

#define CEXP  (-28.853900817779268f)  /* -log2(e)/0.05 */
#define ESH   (14.0f)                 /* E' = 2^(M*CEXP + 14) in fp16 */
#define L2TAU (9.965784284662087f)    /* log2(1000) */

typedef unsigned int u32;

__device__ __forceinline__ float fexp2(float x) { return __builtin_amdgcn_exp2f(x); }
__device__ __forceinline__ float flog2(float x) { return __builtin_amdgcn_logf(x); }

__device__ __forceinline__ float nr_rcp(float x) {
    float r = __builtin_amdgcn_rcpf(x);
    return fmaf(r, fmaf(-x, r, 1.0f), r);
}

template <int CTRL>
__device__ __forceinline__ float dppx(float x) {
    return __int_as_float(__builtin_amdgcn_update_dpp(
        0, __float_as_int(x), CTRL, 0xF, 0xF, true));
}

__device__ __forceinline__ float bfly_sum(float x) {
    x += dppx<0xB1>(x);            // xor1 (quad_perm)
    x += dppx<0x4E>(x);            // xor2 (quad_perm)
    x += dppx<0x141>(x);           // xor4 (half_mirror)
    x += dppx<0x140>(x);           // xor8 (mirror)
    x += __shfl_xor(x, 16, 64);
    x += __shfl_xor(x, 32, 64);
    return x;
}
__device__ __forceinline__ float bfly_max(float x) {
    x = fmaxf(x, dppx<0xB1>(x));
    x = fmaxf(x, dppx<0x4E>(x));
    x = fmaxf(x, dppx<0x141>(x));
    x = fmaxf(x, dppx<0x140>(x));
    x = fmaxf(x, __shfl_xor(x, 16, 64));
    x = fmaxf(x, __shfl_xor(x, 32, 64));
    return x;
}

// accLo += f16lo(e2)*pLo ; accHi += f16hi(e2)*pHi  (one VALU op each)
__device__ __forceinline__ void fma_mix2(float& accLo, float& accHi, u32 e2,
                                         float pLo, float pHi) {
    asm("v_fma_mix_f32 %0, %2, %3, %0 op_sel_hi:[1,0,0]\n\t"
        "v_fma_mix_f32 %1, %2, %4, %1 op_sel:[1,0,0] op_sel_hi:[1,0,0]"
        : "+v"(accLo), "+v"(accHi)
        : "v"(e2), "v"(pLo), "v"(pHi));
}

// ---------------- Kernel A: E' = fp16(2^(M*CEXP+14)), stored transposed ----------------
__global__ __launch_bounds__(256)
void prep_exp_t(const float* __restrict__ X, float* __restrict__ out)
{
    const int blk  = blockIdx.x;
    const int b    = blk >> 4;
    const int tile = blk & 15;
    const int i0   = (tile >> 2) << 7;
    const int j0   = (tile & 3) << 7;
    const int tid  = threadIdx.x;

    const float* __restrict__ Mb = X + (size_t)b * (BN * BN);
    _Float16* __restrict__ Et = reinterpret_cast<_Float16*>(out + (size_t)b * (BN * BN));

    __shared__ _Float16 T[128][130];

    #pragma unroll
    for (int k = 0; k < 16; ++k) {
        int idx = tid + (k << 8);
        int fi  = idx >> 5;
        int fj  = idx & 31;
        float4 m = *reinterpret_cast<const float4*>(Mb + (size_t)(i0 + fi) * BN + j0 + (fj << 2));
        T[(fj << 2) + 0][fi] = (_Float16)fexp2(fmaf(m.x, CEXP, ESH));
        T[(fj << 2) + 1][fi] = (_Float16)fexp2(fmaf(m.y, CEXP, ESH));
        T[(fj << 2) + 2][fi] = (_Float16)fexp2(fmaf(m.z, CEXP, ESH));
        T[(fj << 2) + 3][fi] = (_Float16)fexp2(fmaf(m.w, CEXP, ESH));
    }
    __syncthreads();
    #pragma unroll
    for (int k = 0; k < 32; ++k) {
        int o  = tid + (k << 8);
        int j  = o >> 6;
        int c2 = o & 63;
        u32 val = *reinterpret_cast<const u32*>(&T[j][c2 << 1]);
        *reinterpret_cast<u32*>(Et + (size_t)(j0 + j) * BN + i0 + (c2 << 1)) = val;
    }
}

// ---------------- Kernel B: 50 iterations; 24 cols global + 8 cols LDS per wave ----------
__global__ __launch_bounds__(1024, 4)
void sinkhorn_iter3(const float* __restrict__ X, float* __restrict__ out,
                    float* __restrict__ cucv)
{
    const int b    = blockIdx.x;
    const int t    = threadIdx.x;
    const int lane = t & 63;
    const int w    = t >> 6;            // 0..15

    const u32* __restrict__ Et4 =
        reinterpret_cast<const u32*>(out + (size_t)b * (BN * BN));

    __shared__ float ah[BN], bh[BN], lu[BN], lv[BN], pv[BN];   // 10 KB
    __shared__ float tpart[8][BN];                             // 16 KB
    __shared__ float wmaxlu[8], wmaxlv[16];
    __shared__ uint4 stage[16][8][64];                         // 128 KB, wave-private

    if (t < BN) {
        ah[t] = 0.f; bh[t] = 0.f;
        lu[t] = -9.f; lv[t] = -9.f;
        pv[t] = 0x1p-9f;
    }

    const int jb0 = w << 5;              // 32 columns per wave

    // stage cols jb0+24 .. jb0+31 into LDS once (iteration-invariant, wave-private)
    #pragma unroll
    for (int c = 0; c < 8; ++c)
        stage[w][c][lane] =
            *reinterpret_cast<const uint4*>(Et4 + (size_t)(jb0 + 24 + c) * 256 + (lane << 2));

    uint4 e[4], f[4];
    #pragma unroll
    for (int c = 0; c < 4; ++c)          // preload cols 0..3
        e[c] = *reinterpret_cast<const uint4*>(Et4 + (size_t)(jb0 + c) * 256 + (lane << 2));

    __syncthreads();

    for (int it = 0; it < NITER; ++it) {
        float pr[8];
        *reinterpret_cast<float4*>(&pr[0]) = *reinterpret_cast<const float4*>(&pv[lane * 8]);
        *reinterpret_cast<float4*>(&pr[4]) = *reinterpret_cast<const float4*>(&pv[lane * 8 + 4]);

        float acc[8] = {0, 0, 0, 0, 0, 0, 0, 0};
        float vml = -1e30f;

        auto dogroup = [&](const uint4* eg, int jb) {
            const float4 bh4 = *reinterpret_cast<const float4*>(&bh[jb]);
            float q[4], lvv[4];
            #pragma unroll
            for (int c = 0; c < 4; ++c) {
                float s0 = 0.f, s1 = 0.f;
                fma_mix2(s0, s1, eg[c].x, pr[0], pr[1]);
                fma_mix2(s0, s1, eg[c].y, pr[2], pr[3]);
                fma_mix2(s0, s1, eg[c].z, pr[4], pr[5]);
                fma_mix2(s0, s1, eg[c].w, pr[6], pr[7]);
                float s = bfly_sum(s0 + s1) * 0x1p-14f;
                q[c] = nr_rcp(s);
                const float bj = (c == 0) ? bh4.x : (c == 1) ? bh4.y : (c == 2) ? bh4.z : bh4.w;
                lvv[c] = -bj - flog2(s);
                vml = fmaxf(vml, lvv[c]);
            }
            if (lane == 0)
                *reinterpret_cast<float4*>(&lv[jb]) = make_float4(lvv[0], lvv[1], lvv[2], lvv[3]);
            #pragma unroll
            for (int c = 0; c < 4; ++c) {
                fma_mix2(acc[0], acc[1], eg[c].x, q[c], q[c]);
                fma_mix2(acc[2], acc[3], eg[c].y, q[c], q[c]);
                fma_mix2(acc[4], acc[5], eg[c].z, q[c], q[c]);
                fma_mix2(acc[6], acc[7], eg[c].w, q[c], q[c]);
            }
        };

        // 6 global groups of 4 (cols 0..23), 4-deep prefetch; g==5 prefetches next iter's 0..3
        #pragma unroll
        for (int g = 0; g < 6; ++g) {
            const int jb = jb0 + (g << 2);
            const int jn = (g < 5) ? (jb + 4) : jb0;
            #pragma unroll
            for (int c = 0; c < 4; ++c)
                f[c] = *reinterpret_cast<const uint4*>(Et4 + (size_t)(jn + c) * 256 + (lane << 2));
            dogroup(e, jb);
            #pragma unroll
            for (int c = 0; c < 4; ++c) e[c] = f[c];
        }
        // 2 LDS groups of 4 (cols 24..31)
        #pragma unroll
        for (int g = 0; g < 2; ++g) {
            uint4 el[4];
            #pragma unroll
            for (int c = 0; c < 4; ++c) el[c] = stage[w][(g << 2) + c][lane];
            dogroup(el, jb0 + 24 + (g << 2));
        }

        // ---- two-phase tpart fold: waves 0-7 write, waves 8-15 add ----
        if (w < 8) {
            *reinterpret_cast<float4*>(&tpart[w][lane * 8]) =
                make_float4(acc[0], acc[1], acc[2], acc[3]);
            *reinterpret_cast<float4*>(&tpart[w][lane * 8 + 4]) =
                make_float4(acc[4], acc[5], acc[6], acc[7]);
        }
        if (lane == 0) wmaxlv[w] = vml;
        __syncthreads();
        if (w >= 8) {
            float4* p0 = reinterpret_cast<float4*>(&tpart[w - 8][lane * 8]);
            float4* p1 = reinterpret_cast<float4*>(&tpart[w - 8][lane * 8 + 4]);
            float4 o0 = *p0, o1 = *p1;
            o0.x += acc[0]; o0.y += acc[1]; o0.z += acc[2]; o0.w += acc[3];
            o1.x += acc[4]; o1.y += acc[5]; o1.z += acc[6]; o1.w += acc[7];
            *p0 = o0; *p1 = o1;
        }
        __syncthreads();

        float lun = 0.f, tt = 0.f;
        if (t < BN) {
            float p0 = 0, p1 = 0, p2 = 0, p3 = 0;
            #pragma unroll
            for (int w2 = 0; w2 < 8; w2 += 4) {
                p0 += tpart[w2 + 0][t];
                p1 += tpart[w2 + 1][t];
                p2 += tpart[w2 + 2][t];
                p3 += tpart[w2 + 3][t];
            }
            tt  = ((p0 + p1) + (p2 + p3)) * 0x1p-14f;
            lun = -ah[t] - flog2(tt);
            float m = bfly_max(lun);
            if (lane == 0) wmaxlu[w] = m;
        }
        __syncthreads();

        if (t < BN) {
            float mlu = wmaxlu[0], mlv = wmaxlv[0];
            #pragma unroll
            for (int i2 = 1; i2 < 8; ++i2)  mlu = fmaxf(mlu, wmaxlu[i2]);
            #pragma unroll
            for (int i2 = 1; i2 < 16; ++i2) mlv = fmaxf(mlv, wmaxlv[i2]);
            if (mlu > L2TAU || mlv > L2TAU) {
                float an = ah[t] + lun;
                ah[t] = an;
                lu[t] = -9.f;
                pv[t] = fexp2(an - 9.0f);
                bh[t] += lv[t];
                lv[t] = -9.f;
            } else {
                lu[t] = lun;
                pv[t] = nr_rcp(tt);
            }
        }
        __syncthreads();
    }

    if (cucv != nullptr) {
        if (t < BN) {
            cucv[(size_t)b * 1024 + t]       = ah[t] + lu[t];
            cucv[(size_t)b * 1024 + 512 + t] = bh[t] + lv[t];
        }
    } else {
        // fused fallback epilogue (ws too small)
        if (t < BN) {
            pv[t] = ah[t] + lu[t];
            lv[t] = bh[t] + lv[t];
        }
        __syncthreads();
        const int j  = t & 511;
        const int i0 = (t >> 9) * 256;
        const float cvj = lv[j];
        const float* __restrict__ Mb = X + (size_t)b * (BN * BN);
        float* __restrict__ Gb = out + (size_t)b * (BN * BN);
        #pragma unroll 4
        for (int i = i0; i < i0 + 256; ++i)
            Gb[(size_t)i * BN + j] = fexp2(fmaf(Mb[(size_t)i * BN + j], CEXP, pv[i] + cvj));
    }
}

// ---------------- Kernel C: Gamma epilogue on the full chip ----------------
__global__ __launch_bounds__(256)
void gamma_out(const float* __restrict__ X, float* __restrict__ out,
               const float* __restrict__ cucv)
{
    const int blk  = blockIdx.x;
    const int b    = blk >> 4;
    const int tile = blk & 15;       // 32 rows per tile
    const int tid  = threadIdx.x;
    const int i0   = tile << 5;

    __shared__ float cu[32];
    __shared__ float cv[BN];

    if (tid < 32) cu[tid] = cucv[(size_t)b * 1024 + i0 + tid];
    cv[tid]        = cucv[(size_t)b * 1024 + 512 + tid];
    cv[tid + 256]  = cucv[(size_t)b * 1024 + 768 + tid];
    __syncthreads();

    const float* __restrict__ Mb = X + (size_t)b * (BN * BN);
    float* __restrict__ Gb = out + (size_t)b * (BN * BN);
    const float4* __restrict__ cv4 = reinterpret_cast<const float4*>(cv);

    #pragma unroll
    for (int k = 0; k < 16; ++k) {
        int idx = tid + (k << 8);        // 0..4095 float4s in this 32x512 tile
        int r   = idx >> 7;              // 0..31
        int c4  = idx & 127;             // float4 column index
        int i   = i0 + r;
        float4 m = *reinterpret_cast<const float4*>(Mb + (size_t)i * BN + (c4 << 2));
        float4 c = cv4[c4];
        float cui = cu[r];
        float4 g;
        g.x = fexp2(fmaf(m.x, CEXP, cui + c.x));
        g.y = fexp2(fmaf(m.y, CEXP, cui + c.y));
        g.z = fexp2(fmaf(m.z, CEXP, cui + c.z));
        g.w = fexp2(fmaf(m.w, CEXP, cui + c.w));
        *reinterpret_cast<float4*>(Gb + (size_t)i * BN + (c4 << 2)) = g;
    }
}

extern "C" void kernel_launch(void* const* d_in, const int* in_sizes, int n_in,
                              void* d_out, int out_size, void* d_ws, size_t ws_size,
                              hipStream_t stream)
{
    const float* X = (const float*)d_in[0];
    float* out = (float*)d_out;
    const int batch = in_sizes[0] / (BN * BN);   // 128

    prep_exp_t<<<batch * 16, 256, 0, stream>>>(X, out);

    const size_t cucv_bytes = (size_t)batch * 1024 * sizeof(float);  // 512 KB
    if (ws_size >= cucv_bytes) {
        float* cucv = (float*)d_ws;
        sinkhorn_iter3<<<batch, 1024, 0, stream>>>(X, out, cucv);
        gamma_out<<<batch * 16, 256, 0, stream>>>(X, out, cucv);
    } else {
        sinkhorn_iter3<<<batch, 1024, 0, stream>>>(X, out, nullptr);
    }
}